// Round 15
// baseline (263.815 us; speedup 1.0000x reference)
//
#include <hip/hip_runtime.h>
#include <cstdint>
#include <cmath>

#define RLN2 1.44269504088896340736f

typedef __attribute__((ext_vector_type(8))) short short8;
typedef __attribute__((ext_vector_type(4))) short short4v;
typedef __attribute__((ext_vector_type(4))) float f32x4;
typedef __attribute__((ext_vector_type(16))) float f32x16;
typedef __attribute__((ext_vector_type(4))) unsigned int uint4v;
typedef __attribute__((ext_vector_type(2))) unsigned int uint2v;

__device__ __forceinline__ unsigned short f2bf(float f) {
  unsigned int u = __float_as_uint(f);
  u += 0x7fffu + ((u >> 16) & 1u);
  return (unsigned short)(u >> 16);
}

__device__ __forceinline__ unsigned int cvt_pk_bf16(float lo, float hi) {
  unsigned int r;
  asm("v_cvt_pk_bf16_f32 %0, %1, %2" : "=v"(r) : "v"(lo), "v"(hi));
  return r;
}

__device__ __forceinline__ float fast_exp2(float x) {
#if __has_builtin(__builtin_amdgcn_exp2f)
  return __builtin_amdgcn_exp2f(x);
#else
  return exp2f(x);
#endif
}

__device__ __forceinline__ void gload16(const void* g, void* l) {
  __builtin_amdgcn_global_load_lds(
      (const __attribute__((address_space(1))) unsigned int*)g,
      (__attribute__((address_space(3))) unsigned int*)l,
      16, 0, 0);
}

// ---------------- fused prep: hs->bf16, W->bf16, seg fill (one launch) ----------------
__global__ void __launch_bounds__(256) k_prep(const float* __restrict__ hs,
                                              const float* __restrict__ Wq,
                                              const float* __restrict__ Wk,
                                              const float* __restrict__ Wv,
                                              const int* __restrict__ seg_ids,
                                              const float* __restrict__ seg_table,
                                              unsigned short* __restrict__ hsb,
                                              unsigned short* __restrict__ Wcat,
                                              unsigned short* __restrict__ Kaug) {
  int blk = blockIdx.x;
  if (blk < 4096) {
    size_t i = (size_t)blk * 256 + threadIdx.x;
    const float4* s = (const float4*)hs + i * 2;
    float4 a = s[0], b = s[1];
    short8 o;
    o[0] = (short)f2bf(a.x); o[1] = (short)f2bf(a.y); o[2] = (short)f2bf(a.z); o[3] = (short)f2bf(a.w);
    o[4] = (short)f2bf(b.x); o[5] = (short)f2bf(b.y); o[6] = (short)f2bf(b.z); o[7] = (short)f2bf(b.w);
    ((short8*)hsb)[i] = o;
  } else if (blk < 5632) {
    size_t i = (size_t)(blk - 4096) * 256 + threadIdx.x;
    int e = (int)(i * 8);
    int n = e >> 10, c = e & 1023;
    const float* row = (n < 1024) ? (Wq + (size_t)n * 1024)
                     : (n < 2048) ? (Wk + (size_t)(n - 1024) * 1024)
                                  : (Wv + (size_t)(n - 2048) * 1024);
    const float4* s = (const float4*)(row + c);
    float4 a = s[0], b = s[1];
    short8 o;
    o[0] = (short)f2bf(a.x); o[1] = (short)f2bf(a.y); o[2] = (short)f2bf(a.z); o[3] = (short)f2bf(a.w);
    o[4] = (short)f2bf(b.x); o[5] = (short)f2bf(b.y); o[6] = (short)f2bf(b.z); o[7] = (short)f2bf(b.w);
    ((short8*)Wcat)[i] = o;
  } else {
    size_t i = (size_t)(blk - 5632) * 256 + threadIdx.x;
    int e = (int)(i * 8);
    int jl = e >> 10;
    int r  = e & 1023;
    int sid = seg_ids[jl];
    const float4* s = (const float4*)(seg_table + (size_t)sid * 1024 + r);
    float4 a = s[0], b = s[1];
    short8 o;
    o[0] = (short)f2bf(a.x); o[1] = (short)f2bf(a.y); o[2] = (short)f2bf(a.z); o[3] = (short)f2bf(a.w);
    o[4] = (short)f2bf(b.x); o[5] = (short)f2bf(b.y); o[6] = (short)f2bf(b.z); o[7] = (short)f2bf(b.w);
    int b_ = jl >> 11, j = jl & 2047;
    int h = r >> 6, d = r & 63;
    size_t off = ((size_t)(b_ * 16 + h) * 2048 + j) * 128 + 64 + d;
    *(short8*)(Kaug + off) = o;
  }
}

// ---------------- fused QKV GEMM (NT), double-buffered single-barrier K-loop ----------------
// attn's proven pattern: prefetch kt+1 into the other LDS buffer at iteration start,
// ONE __syncthreads at end of iteration (33 barriers vs 64). LDS 32KB total.
// Q/K blocks (seg<2): swapped operands mfma(W,hs) -> 8B packed stores.
// V blocks (seg==2): original order, k-permuted 8B Vt stores.
__global__ void __launch_bounds__(256) k_gemm(const unsigned short* __restrict__ A,
                                              const unsigned short* __restrict__ Bw,
                                              const float* __restrict__ bq,
                                              const float* __restrict__ bv,
                                              const float* __restrict__ bqs,
                                              unsigned short* __restrict__ Qaug,
                                              unsigned short* __restrict__ Kaug,
                                              unsigned short* __restrict__ Vt) {
  __shared__ unsigned short As[2][128 * 32];
  __shared__ unsigned short Bs[2][128 * 32];
  int n0 = blockIdx.x * 128;
  int m0 = blockIdx.y * 128;
  int tid = threadIdx.x;
  int w = tid >> 6, lane = tid & 63;
  int wr = (w >> 1) * 64, wc = (w & 1) * 64;
  int rA = lane & 15;
  int kg = (lane >> 4) * 16;
  int seg = n0 >> 10;  // 0=q, 1=k, 2=v
  f32x4 acc[4][4] = {};
  const char* Ab = (const char*)A;
  const char* Bb = (const char*)Bw;

  // staging lane decomp (hoisted): chunk = w*2+c covers rows [chunk*16, chunk*16+16)
  int st_row = lane >> 2, st_cb = (lane & 3) * 16;  // row within chunk, byte within 64B row

  // ---- prologue: stage kt=0 into buffer 0 ----
#pragma unroll
  for (int c = 0; c < 2; ++c) {
    int chunk = w * 2 + c;
    int row = chunk * 16 + st_row;
    gload16(Ab + (size_t)(m0 + row) * 2048 + st_cb, (char*)As[0] + chunk * 1024);
    gload16(Bb + (size_t)(n0 + row) * 2048 + st_cb, (char*)Bs[0] + chunk * 1024);
  }
  __syncthreads();

  for (int kt = 0; kt < 32; ++kt) {
    int cur = kt & 1, nxt = cur ^ 1;
    if (kt < 31) {  // prefetch kt+1 into the other buffer (drains at end barrier)
      int kb1 = (kt + 1) * 64;
#pragma unroll
      for (int c = 0; c < 2; ++c) {
        int chunk = w * 2 + c;
        int row = chunk * 16 + st_row;
        gload16(Ab + (size_t)(m0 + row) * 2048 + kb1 + st_cb, (char*)As[nxt] + chunk * 1024);
        gload16(Bb + (size_t)(n0 + row) * 2048 + kb1 + st_cb, (char*)Bs[nxt] + chunk * 1024);
      }
    }
    short8 af[4], bfr[4];
#pragma unroll
    for (int m = 0; m < 4; ++m)
      af[m] = *(const short8*)((const char*)As[cur] + (wr + m * 16 + rA) * 64 + kg);
#pragma unroll
    for (int n = 0; n < 4; ++n)
      bfr[n] = *(const short8*)((const char*)Bs[cur] + (wc + n * 16 + rA) * 64 + kg);
    if (seg == 2) {
#pragma unroll
      for (int m = 0; m < 4; ++m)
#pragma unroll
        for (int n = 0; n < 4; ++n)
          acc[m][n] = __builtin_amdgcn_mfma_f32_16x16x32_bf16(af[m], bfr[n], acc[m][n], 0, 0, 0);
    } else {
#pragma unroll
      for (int m = 0; m < 4; ++m)
#pragma unroll
        for (int n = 0; n < 4; ++n)
          acc[m][n] = __builtin_amdgcn_mfma_f32_16x16x32_bf16(bfr[n], af[m], acc[m][n], 0, 0, 0);
    }
    __syncthreads();  // single barrier: prefetch drained; buffers swap
  }

  int colbase = n0 & 1023;
  int g = lane >> 4;
  if (seg == 2) {
#pragma unroll
    for (int n = 0; n < 4; ++n) {
      int o = colbase + wc + n * 16 + (lane & 15);
      int h = o >> 6, d = o & 63;
      float bias = bv[o];
#pragma unroll
      for (int m = 0; m < 4; ++m) {
        int i = m0 + wr + m * 16 + g * 4;  // r=0 token
        int b_ = i >> 11, sdx = i & 2047;
        int bh = b_ * 16 + h;
        int pos = (sdx & ~63) + 32 * ((m >> 1) & 1) + 16 * (m & 1) + 8 * (g & 1) + 4 * ((g >> 1) & 1);
        short4v pv;
#pragma unroll
        for (int r = 0; r < 4; ++r)
          pv[r] = (short)f2bf(acc[m][n][r] + bias);
        *(short4v*)(Vt + (size_t)bh * 131072 + (size_t)d * 2048 + pos) = pv;
      }
    }
  } else {
    int tok16 = lane & 15, g4 = g * 4;
#pragma unroll
    for (int m = 0; m < 4; ++m) {
      int i = m0 + wr + m * 16 + tok16;
      int b_ = i >> 11, sdx = i & 2047;
#pragma unroll
      for (int n = 0; n < 4; ++n) {
        int o0 = colbase + wc + n * 16 + g4;
        int h = o0 >> 6, d0 = o0 & 63;
        size_t tok = (size_t)(b_ * 16 + h) * 2048 + sdx;
        if (seg == 0) {
          f32x4 bqv = *(const f32x4*)(bq + o0);
          f32x4 bqs4 = *(const f32x4*)(bqs + o0);
          float qv0 = acc[m][n][0] + bqv[0], qv1 = acc[m][n][1] + bqv[1];
          float qv2 = acc[m][n][2] + bqv[2], qv3 = acc[m][n][3] + bqv[3];
          const float sc = 0.125f * RLN2;
          uint2v p1;
          p1[0] = cvt_pk_bf16(qv0 * sc, qv1 * sc);
          p1[1] = cvt_pk_bf16(qv2 * sc, qv3 * sc);
          *(uint2v*)(Qaug + tok * 128 + d0) = p1;
          uint2v p2;
          p2[0] = cvt_pk_bf16((qv0 + bqs4[0]) * RLN2, (qv1 + bqs4[1]) * RLN2);
          p2[1] = cvt_pk_bf16((qv2 + bqs4[2]) * RLN2, (qv3 + bqs4[3]) * RLN2);
          *(uint2v*)(Qaug + tok * 128 + 64 + d0) = p2;
        } else {
          uint2v p1;
          p1[0] = cvt_pk_bf16(acc[m][n][0], acc[m][n][1]);
          p1[1] = cvt_pk_bf16(acc[m][n][2], acc[m][n][3]);
          *(uint2v*)(Kaug + tok * 128 + d0) = p1;
        }
      }
    }
  }
}

// ---------------- flash attention, 32x32x16 MFMA, 32 q-rows/wave ----------------
// R9/R13 VERBATIM (proven 159.5us).
__global__ void __launch_bounds__(512, 4) k_attn(const unsigned short* __restrict__ Qaug,
                                                 const unsigned short* __restrict__ Kaug,
                                                 const unsigned short* __restrict__ Vt,
                                                 const float* __restrict__ mask,
                                                 float* __restrict__ out) {
  __shared__ char smem[49152];
  char* Ksb = smem;          // 2 x 16K
  char* Vsb = smem + 32768;  // 2 x 8K

  int qt = blockIdx.x, h = blockIdx.y, b_ = blockIdx.z;
  int bh = b_ * 16 + h;
  int i0 = qt * 256;
  int tid = threadIdx.x, w = tid >> 6, lane = tid & 63;
  int q = lane & 31, hi = lane >> 5;
  int swzq = (q & 7) << 4;
  const char* Qg = (const char*)Qaug + (size_t)bh * 2048 * 256;
  const char* Kg = (const char*)Kaug + (size_t)bh * 2048 * 256;
  const char* Vg = (const char*)Vt + (size_t)bh * 64 * 4096;
  const float* maskb = mask + (size_t)b_ * 2048;

  int foff[8];
#pragma unroll
  for (int ds = 0; ds < 8; ++ds)
    foff[ds] = (ds * 32 + hi * 16) ^ swzq;

  int kst_row = lane >> 4, kst_x = (lane & 15) * 16;
  int vst_dv = lane >> 3;
  int vst_x = ((lane & 7) * 16) ^ ((vst_dv & 7) << 4);

  // ---- stage tile 0 ----
#pragma unroll
  for (int c = 0; c < 2; ++c) {
    int ck = w * 2 + c;
    int krow = ck * 4 + kst_row;
    gload16(Kg + (size_t)krow * 256 + (kst_x ^ ((krow & 7) << 4)), Ksb + ck * 1024);
  }
  {
    int dv = w * 8 + vst_dv;
    gload16(Vg + (size_t)dv * 4096 + vst_x, Vsb + w * 1024);
  }

  short8 qf[8];
  {
    const char* qrow = Qg + (size_t)(i0 + w * 32 + q) * 256 + hi * 16;
#pragma unroll
    for (int ds = 0; ds < 8; ++ds)
      qf[ds] = *(const short8*)(qrow + ds * 32);
  }
  __syncthreads();  // K0/V0 resident

  float m_run = -1e30f, l_run = 0.f;
  f32x16 accO[2] = {};

  for (int t = 0; t < 32; ++t) {
    int cur = t & 1, nxt = cur ^ 1;
    int j0 = t * 64;
    if (t < 31) {
      int jn = j0 + 64;
      char* kd = Ksb + nxt * 16384;
      char* vd = Vsb + nxt * 8192;
#pragma unroll
      for (int c = 0; c < 2; ++c) {
        int ck = w * 2 + c;
        int krow = ck * 4 + kst_row;
        gload16(Kg + (size_t)(jn + krow) * 256 + (kst_x ^ ((krow & 7) << 4)), kd + ck * 1024);
      }
      {
        int dv = w * 8 + vst_dv;
        gload16(Vg + (size_t)dv * 4096 + jn * 2 + vst_x, vd + w * 1024);
      }
    }
    const char* kq = Ksb + cur * 16384 + q * 256;
    const char* vq = Vsb + cur * 8192 + q * 128;

    // ---- S^T = K . Q^T ----
    f32x16 s0 = {}, s1 = {};
    __builtin_amdgcn_s_setprio(1);
#pragma unroll
    for (int ds = 0; ds < 8; ++ds) {
      short8 kf0 = *(const short8*)(kq + foff[ds]);
      short8 kf1 = *(const short8*)(kq + foff[ds] + 8192);
      s0 = __builtin_amdgcn_mfma_f32_32x32x16_bf16(kf0, qf[ds], s0, 0, 0, 0);
      s1 = __builtin_amdgcn_mfma_f32_32x32x16_bf16(kf1, qf[ds], s1, 0, 0, 0);
    }
    __builtin_amdgcn_s_setprio(0);

    // ---- mask add via fma(mv, RLN2, s) ----
#pragma unroll
    for (int c = 0; c < 4; ++c) {
      f32x4 mv0 = *(const f32x4*)(maskb + j0 + 8 * c + 4 * hi);
      f32x4 mv1 = *(const f32x4*)(maskb + j0 + 32 + 8 * c + 4 * hi);
#pragma unroll
      for (int r = 0; r < 4; ++r) {
        s0[4 * c + r] = fmaf(mv0[r], RLN2, s0[4 * c + r]);
        s1[4 * c + r] = fmaf(mv1[r], RLN2, s1[4 * c + r]);
      }
    }

    // ---- online softmax ----
    {
      f32x16 mx;
#pragma unroll
      for (int i = 0; i < 16; ++i) mx[i] = fmaxf(s0[i], s1[i]);
#pragma unroll
      for (int i = 0; i < 8; ++i) mx[i] = fmaxf(mx[i], mx[i + 8]);
#pragma unroll
      for (int i = 0; i < 4; ++i) mx[i] = fmaxf(mx[i], mx[i + 4]);
      float tm = fmaxf(fmaxf(mx[0], mx[1]), fmaxf(mx[2], mx[3]));
      tm = fmaxf(tm, __shfl_xor(tm, 32));

      if (__any(tm > m_run + 8.0f)) {  // defer-max (T13)
        float mn = fmaxf(m_run, tm);
        float alpha = fast_exp2(m_run - mn);
        m_run = mn;
        l_run *= alpha;
#pragma unroll
        for (int i = 0; i < 16; ++i) { accO[0][i] *= alpha; accO[1][i] *= alpha; }
      }
    }
    {
      f32x16 es;
#pragma unroll
      for (int i = 0; i < 16; ++i) {
        float e0 = fast_exp2(s0[i] - m_run);
        float e1 = fast_exp2(s1[i] - m_run);
        s0[i] = e0; s1[i] = e1;
        es[i] = e0 + e1;
      }
#pragma unroll
      for (int i = 0; i < 8; ++i) es[i] += es[i + 8];
#pragma unroll
      for (int i = 0; i < 4; ++i) es[i] += es[i + 4];
      float ps = (es[0] + es[1]) + (es[2] + es[3]);
      ps += __shfl_xor(ps, 32);
      l_run += ps;
    }

    // ---- pack P ----
    uint4v pk[4];
#pragma unroll
    for (int ks = 0; ks < 4; ++ks) {
      int o = 8 * (ks & 1);
      const f32x16& sv = (ks < 2) ? s0 : s1;
      pk[ks][0] = cvt_pk_bf16(sv[o + 0], sv[o + 1]);
      pk[ks][1] = cvt_pk_bf16(sv[o + 2], sv[o + 3]);
      pk[ks][2] = cvt_pk_bf16(sv[o + 4], sv[o + 5]);
      pk[ks][3] = cvt_pk_bf16(sv[o + 6], sv[o + 7]);
    }

    // ---- O += Vt-frag . P ----
    __builtin_amdgcn_s_setprio(1);
#pragma unroll
    for (int ks = 0; ks < 4; ++ks) {
      short8 pf = __builtin_bit_cast(short8, pk[ks]);
      short8 vf0 = *(const short8*)(vq + foff[ks]);
      short8 vf1 = *(const short8*)(vq + foff[ks] + 4096);
      accO[0] = __builtin_amdgcn_mfma_f32_32x32x16_bf16(vf0, pf, accO[0], 0, 0, 0);
      accO[1] = __builtin_amdgcn_mfma_f32_32x32x16_bf16(vf1, pf, accO[1], 0, 0, 0);
    }
    __builtin_amdgcn_s_setprio(0);
    __syncthreads();  // single barrier: prefetch drained; buffers swap
  }

  float inv = 1.0f / l_run;
  float* orow = out + ((size_t)b_ * 2048 + i0 + w * 32 + q) * 1024 + h * 64;
#pragma unroll
  for (int vh = 0; vh < 2; ++vh) {
#pragma unroll
    for (int c = 0; c < 4; ++c) {
      f32x4 o;
      o[0] = accO[vh][4 * c + 0] * inv;
      o[1] = accO[vh][4 * c + 1] * inv;
      o[2] = accO[vh][4 * c + 2] * inv;
      o[3] = accO[vh][4 * c + 3] * inv;
      *(f32x4*)(orow + vh * 32 + 8 * c + 4 * hi) = o;
    }
  }
}

extern "C" void kernel_launch(void* const* d_in, const int* in_sizes, int n_in,
                              void* d_out, int out_size, void* d_ws, size_t ws_size,
                              hipStream_t stream) {
  (void)in_sizes; (void)n_in; (void)out_size; (void)ws_size;
  const float* hs        = (const float*)d_in[0];
  const float* mask      = (const float*)d_in[1];
  const int*   seg_ids   = (const int*)d_in[2];
  const float* Wq        = (const float*)d_in[3];
  const float* bq        = (const float*)d_in[4];
  const float* Wk        = (const float*)d_in[5];
  const float* Wv        = (const float*)d_in[6];
  const float* bv        = (const float*)d_in[7];
  const float* seg_table = (const float*)d_in[8];
  const float* bqs       = (const float*)d_in[9];
  float* out = (float*)d_out;
  char* ws = (char*)d_ws;

  unsigned short* hsb  = (unsigned short*)(ws + 0);         // 16 MiB
  unsigned short* Wcat = (unsigned short*)(ws + 16777216);  // 6 MiB
  unsigned short* Qaug = (unsigned short*)(ws + 23068672);  // 32 MiB
  unsigned short* Kaug = (unsigned short*)(ws + 56623104);  // 32 MiB
  unsigned short* Vt   = (unsigned short*)(ws + 90177536);  // 16 MiB

  k_prep<<<dim3(9728), dim3(256), 0, stream>>>(hs, Wq, Wk, Wv, seg_ids, seg_table,
                                               hsb, Wcat, Kaug);
  k_gemm<<<dim3(24, 64), dim3(256), 0, stream>>>(hsb, Wcat, bq, bv, bqs, Qaug, Kaug, Vt);
  k_attn<<<dim3(8, 16, 4), dim3(512), 0, stream>>>(Qaug, Kaug, Vt, mask, out);
}

// Round 16
// 254.015 us; speedup vs baseline: 1.0386x; 1.0386x over previous
//
#include <hip/hip_runtime.h>
#include <cstdint>
#include <cmath>

#define RLN2 1.44269504088896340736f

typedef __attribute__((ext_vector_type(8))) short short8;
typedef __attribute__((ext_vector_type(4))) short short4v;
typedef __attribute__((ext_vector_type(4))) float f32x4;
typedef __attribute__((ext_vector_type(16))) float f32x16;
typedef __attribute__((ext_vector_type(4))) unsigned int uint4v;
typedef __attribute__((ext_vector_type(2))) unsigned int uint2v;

__device__ __forceinline__ unsigned short f2bf(float f) {
  unsigned int u = __float_as_uint(f);
  u += 0x7fffu + ((u >> 16) & 1u);
  return (unsigned short)(u >> 16);
}

__device__ __forceinline__ unsigned int cvt_pk_bf16(float lo, float hi) {
  unsigned int r;
  asm("v_cvt_pk_bf16_f32 %0, %1, %2" : "=v"(r) : "v"(lo), "v"(hi));
  return r;
}

__device__ __forceinline__ float fast_exp2(float x) {
#if __has_builtin(__builtin_amdgcn_exp2f)
  return __builtin_amdgcn_exp2f(x);
#else
  return exp2f(x);
#endif
}

__device__ __forceinline__ void gload16(const void* g, void* l) {
  __builtin_amdgcn_global_load_lds(
      (const __attribute__((address_space(1))) unsigned int*)g,
      (__attribute__((address_space(3))) unsigned int*)l,
      16, 0, 0);
}

// ---------------- fused prep: hs->bf16, W->bf16, seg fill (one launch) ----------------
// blocks [0,4096): hs convert; [4096,5632): W convert; [5632,9728): seg fill.
// seg fill writes Kaug[tok*128 + 64+d] only -> disjoint from gemm's Kaug writes,
// so prep runs BEFORE gemm.
__global__ void __launch_bounds__(256) k_prep(const float* __restrict__ hs,
                                              const float* __restrict__ Wq,
                                              const float* __restrict__ Wk,
                                              const float* __restrict__ Wv,
                                              const int* __restrict__ seg_ids,
                                              const float* __restrict__ seg_table,
                                              unsigned short* __restrict__ hsb,
                                              unsigned short* __restrict__ Wcat,
                                              unsigned short* __restrict__ Kaug) {
  int blk = blockIdx.x;
  if (blk < 4096) {
    size_t i = (size_t)blk * 256 + threadIdx.x;
    const float4* s = (const float4*)hs + i * 2;
    float4 a = s[0], b = s[1];
    short8 o;
    o[0] = (short)f2bf(a.x); o[1] = (short)f2bf(a.y); o[2] = (short)f2bf(a.z); o[3] = (short)f2bf(a.w);
    o[4] = (short)f2bf(b.x); o[5] = (short)f2bf(b.y); o[6] = (short)f2bf(b.z); o[7] = (short)f2bf(b.w);
    ((short8*)hsb)[i] = o;
  } else if (blk < 5632) {
    size_t i = (size_t)(blk - 4096) * 256 + threadIdx.x;
    int e = (int)(i * 8);
    int n = e >> 10, c = e & 1023;
    const float* row = (n < 1024) ? (Wq + (size_t)n * 1024)
                     : (n < 2048) ? (Wk + (size_t)(n - 1024) * 1024)
                                  : (Wv + (size_t)(n - 2048) * 1024);
    const float4* s = (const float4*)(row + c);
    float4 a = s[0], b = s[1];
    short8 o;
    o[0] = (short)f2bf(a.x); o[1] = (short)f2bf(a.y); o[2] = (short)f2bf(a.z); o[3] = (short)f2bf(a.w);
    o[4] = (short)f2bf(b.x); o[5] = (short)f2bf(b.y); o[6] = (short)f2bf(b.z); o[7] = (short)f2bf(b.w);
    ((short8*)Wcat)[i] = o;
  } else {
    size_t i = (size_t)(blk - 5632) * 256 + threadIdx.x;
    int e = (int)(i * 8);
    int jl = e >> 10;
    int r  = e & 1023;
    int sid = seg_ids[jl];
    const float4* s = (const float4*)(seg_table + (size_t)sid * 1024 + r);
    float4 a = s[0], b = s[1];
    short8 o;
    o[0] = (short)f2bf(a.x); o[1] = (short)f2bf(a.y); o[2] = (short)f2bf(a.z); o[3] = (short)f2bf(a.w);
    o[4] = (short)f2bf(b.x); o[5] = (short)f2bf(b.y); o[6] = (short)f2bf(b.z); o[7] = (short)f2bf(b.w);
    int b_ = jl >> 11, j = jl & 2047;
    int h = r >> 6, d = r & 63;
    size_t off = ((size_t)(b_ * 16 + h) * 2048 + j) * 128 + 64 + d;
    *(short8*)(Kaug + off) = o;
  }
}

// ---------------- fused QKV GEMM (NT) ----------------
// R13 verbatim (253.2us config): single-buffered 2-barrier K-loop, 16KB LDS,
// 8 blocks/CU (full grid co-resident in one pass).
// Q/K blocks (seg<2): SWAPPED operands mfma(W,hs) -> lane owns 4 consecutive
// features of one token -> 8B packed stores (4x fewer store instrs).
// V blocks (seg==2): original order, k-permuted 8B Vt stores (layout-dependent).
__global__ void __launch_bounds__(256) k_gemm(const unsigned short* __restrict__ A,
                                              const unsigned short* __restrict__ Bw,
                                              const float* __restrict__ bq,
                                              const float* __restrict__ bv,
                                              const float* __restrict__ bqs,
                                              unsigned short* __restrict__ Qaug,
                                              unsigned short* __restrict__ Kaug,
                                              unsigned short* __restrict__ Vt) {
  __shared__ unsigned short As[128 * 32];
  __shared__ unsigned short Bs[128 * 32];
  int n0 = blockIdx.x * 128;
  int m0 = blockIdx.y * 128;
  int tid = threadIdx.x;
  int w = tid >> 6, lane = tid & 63;
  int wr = (w >> 1) * 64, wc = (w & 1) * 64;
  int rA = lane & 15;
  int kg = (lane >> 4) * 16;
  int seg = n0 >> 10;  // 0=q, 1=k, 2=v
  f32x4 acc[4][4] = {};
  const char* Ab = (const char*)A;
  const char* Bb = (const char*)Bw;

  for (int kt = 0; kt < 32; ++kt) {
    int kb0 = kt * 64;
#pragma unroll
    for (int c = 0; c < 2; ++c) {
      int chunk = w * 2 + c;
      int y = chunk * 1024 + lane * 16;
      int row = y >> 6, colb = y & 63;
      gload16(Ab + (size_t)(m0 + row) * 2048 + kb0 + colb, (char*)As + chunk * 1024);
      gload16(Bb + (size_t)(n0 + row) * 2048 + kb0 + colb, (char*)Bs + chunk * 1024);
    }
    __syncthreads();
    short8 af[4], bfr[4];
#pragma unroll
    for (int m = 0; m < 4; ++m)
      af[m] = *(const short8*)((const char*)As + (wr + m * 16 + rA) * 64 + kg);
#pragma unroll
    for (int n = 0; n < 4; ++n)
      bfr[n] = *(const short8*)((const char*)Bs + (wc + n * 16 + rA) * 64 + kg);
    if (seg == 2) {
#pragma unroll
      for (int m = 0; m < 4; ++m)
#pragma unroll
        for (int n = 0; n < 4; ++n)
          acc[m][n] = __builtin_amdgcn_mfma_f32_16x16x32_bf16(af[m], bfr[n], acc[m][n], 0, 0, 0);
    } else {
#pragma unroll
      for (int m = 0; m < 4; ++m)
#pragma unroll
        for (int n = 0; n < 4; ++n)
          acc[m][n] = __builtin_amdgcn_mfma_f32_16x16x32_bf16(bfr[n], af[m], acc[m][n], 0, 0, 0);
    }
    __syncthreads();
  }

  int colbase = n0 & 1023;
  int g = lane >> 4;
  if (seg == 2) {
    // original layout: lane owns feature o=colbase+wc+n*16+(lane&15), tokens m*16+g*4+r
#pragma unroll
    for (int n = 0; n < 4; ++n) {
      int o = colbase + wc + n * 16 + (lane & 15);
      int h = o >> 6, d = o & 63;
      float bias = bv[o];
#pragma unroll
      for (int m = 0; m < 4; ++m) {
        int i = m0 + wr + m * 16 + g * 4;  // r=0 token
        int b_ = i >> 11, sdx = i & 2047;
        int bh = b_ * 16 + h;
        int pos = (sdx & ~63) + 32 * ((m >> 1) & 1) + 16 * (m & 1) + 8 * (g & 1) + 4 * ((g >> 1) & 1);
        short4v pv;
#pragma unroll
        for (int r = 0; r < 4; ++r)
          pv[r] = (short)f2bf(acc[m][n][r] + bias);
        *(short4v*)(Vt + (size_t)bh * 131072 + (size_t)d * 2048 + pos) = pv;
      }
    }
  } else {
    // swapped layout: lane owns token i=m0+wr+m*16+(lane&15), features n*16+g*4+r
    int tok16 = lane & 15, g4 = g * 4;
#pragma unroll
    for (int m = 0; m < 4; ++m) {
      int i = m0 + wr + m * 16 + tok16;
      int b_ = i >> 11, sdx = i & 2047;
#pragma unroll
      for (int n = 0; n < 4; ++n) {
        int o0 = colbase + wc + n * 16 + g4;
        int h = o0 >> 6, d0 = o0 & 63;
        size_t tok = (size_t)(b_ * 16 + h) * 2048 + sdx;
        if (seg == 0) {
          f32x4 bqv = *(const f32x4*)(bq + o0);
          f32x4 bqs4 = *(const f32x4*)(bqs + o0);
          float qv0 = acc[m][n][0] + bqv[0], qv1 = acc[m][n][1] + bqv[1];
          float qv2 = acc[m][n][2] + bqv[2], qv3 = acc[m][n][3] + bqv[3];
          const float sc = 0.125f * RLN2;
          uint2v p1;
          p1[0] = cvt_pk_bf16(qv0 * sc, qv1 * sc);
          p1[1] = cvt_pk_bf16(qv2 * sc, qv3 * sc);
          *(uint2v*)(Qaug + tok * 128 + d0) = p1;
          uint2v p2;
          p2[0] = cvt_pk_bf16((qv0 + bqs4[0]) * RLN2, (qv1 + bqs4[1]) * RLN2);
          p2[1] = cvt_pk_bf16((qv2 + bqs4[2]) * RLN2, (qv3 + bqs4[3]) * RLN2);
          *(uint2v*)(Qaug + tok * 128 + 64 + d0) = p2;
        } else {
          uint2v p1;
          p1[0] = cvt_pk_bf16(acc[m][n][0], acc[m][n][1]);
          p1[1] = cvt_pk_bf16(acc[m][n][2], acc[m][n][3]);
          *(uint2v*)(Kaug + tok * 128 + d0) = p1;
        }
      }
    }
  }
}

// ---------------- flash attention, 32x32x16 MFMA, 32 q-rows/wave ----------------
// R9/R13 VERBATIM (proven 159.5us): 512 thr / 8 waves / 256 q-rows per block,
// K 2x16K + V 2x8K double buffer, prefetch at tile start, ONE end-of-tile barrier.
__global__ void __launch_bounds__(512, 4) k_attn(const unsigned short* __restrict__ Qaug,
                                                 const unsigned short* __restrict__ Kaug,
                                                 const unsigned short* __restrict__ Vt,
                                                 const float* __restrict__ mask,
                                                 float* __restrict__ out) {
  __shared__ char smem[49152];
  char* Ksb = smem;          // 2 x 16K
  char* Vsb = smem + 32768;  // 2 x 8K

  int qt = blockIdx.x, h = blockIdx.y, b_ = blockIdx.z;
  int bh = b_ * 16 + h;
  int i0 = qt * 256;
  int tid = threadIdx.x, w = tid >> 6, lane = tid & 63;
  int q = lane & 31, hi = lane >> 5;
  int swzq = (q & 7) << 4;
  const char* Qg = (const char*)Qaug + (size_t)bh * 2048 * 256;
  const char* Kg = (const char*)Kaug + (size_t)bh * 2048 * 256;
  const char* Vg = (const char*)Vt + (size_t)bh * 64 * 4096;
  const float* maskb = mask + (size_t)b_ * 2048;

  int foff[8];
#pragma unroll
  for (int ds = 0; ds < 8; ++ds)
    foff[ds] = (ds * 32 + hi * 16) ^ swzq;

  int kst_row = lane >> 4, kst_x = (lane & 15) * 16;
  int vst_dv = lane >> 3;
  int vst_x = ((lane & 7) * 16) ^ ((vst_dv & 7) << 4);

  // ---- stage tile 0 ----
#pragma unroll
  for (int c = 0; c < 2; ++c) {
    int ck = w * 2 + c;
    int krow = ck * 4 + kst_row;
    gload16(Kg + (size_t)krow * 256 + (kst_x ^ ((krow & 7) << 4)), Ksb + ck * 1024);
  }
  {
    int dv = w * 8 + vst_dv;
    gload16(Vg + (size_t)dv * 4096 + vst_x, Vsb + w * 1024);
  }

  short8 qf[8];
  {
    const char* qrow = Qg + (size_t)(i0 + w * 32 + q) * 256 + hi * 16;
#pragma unroll
    for (int ds = 0; ds < 8; ++ds)
      qf[ds] = *(const short8*)(qrow + ds * 32);
  }
  __syncthreads();  // K0/V0 resident

  float m_run = -1e30f, l_run = 0.f;
  f32x16 accO[2] = {};

  for (int t = 0; t < 32; ++t) {
    int cur = t & 1, nxt = cur ^ 1;
    int j0 = t * 64;
    if (t < 31) {
      int jn = j0 + 64;
      char* kd = Ksb + nxt * 16384;
      char* vd = Vsb + nxt * 8192;
#pragma unroll
      for (int c = 0; c < 2; ++c) {
        int ck = w * 2 + c;
        int krow = ck * 4 + kst_row;
        gload16(Kg + (size_t)(jn + krow) * 256 + (kst_x ^ ((krow & 7) << 4)), kd + ck * 1024);
      }
      {
        int dv = w * 8 + vst_dv;
        gload16(Vg + (size_t)dv * 4096 + jn * 2 + vst_x, vd + w * 1024);
      }
    }
    const char* kq = Ksb + cur * 16384 + q * 256;
    const char* vq = Vsb + cur * 8192 + q * 128;

    // ---- S^T = K . Q^T ----
    f32x16 s0 = {}, s1 = {};
    __builtin_amdgcn_s_setprio(1);
#pragma unroll
    for (int ds = 0; ds < 8; ++ds) {
      short8 kf0 = *(const short8*)(kq + foff[ds]);
      short8 kf1 = *(const short8*)(kq + foff[ds] + 8192);
      s0 = __builtin_amdgcn_mfma_f32_32x32x16_bf16(kf0, qf[ds], s0, 0, 0, 0);
      s1 = __builtin_amdgcn_mfma_f32_32x32x16_bf16(kf1, qf[ds], s1, 0, 0, 0);
    }
    __builtin_amdgcn_s_setprio(0);

    // ---- mask add via fma(mv, RLN2, s) ----
#pragma unroll
    for (int c = 0; c < 4; ++c) {
      f32x4 mv0 = *(const f32x4*)(maskb + j0 + 8 * c + 4 * hi);
      f32x4 mv1 = *(const f32x4*)(maskb + j0 + 32 + 8 * c + 4 * hi);
#pragma unroll
      for (int r = 0; r < 4; ++r) {
        s0[4 * c + r] = fmaf(mv0[r], RLN2, s0[4 * c + r]);
        s1[4 * c + r] = fmaf(mv1[r], RLN2, s1[4 * c + r]);
      }
    }

    // ---- online softmax ----
    {
      f32x16 mx;
#pragma unroll
      for (int i = 0; i < 16; ++i) mx[i] = fmaxf(s0[i], s1[i]);
#pragma unroll
      for (int i = 0; i < 8; ++i) mx[i] = fmaxf(mx[i], mx[i + 8]);
#pragma unroll
      for (int i = 0; i < 4; ++i) mx[i] = fmaxf(mx[i], mx[i + 4]);
      float tm = fmaxf(fmaxf(mx[0], mx[1]), fmaxf(mx[2], mx[3]));
      tm = fmaxf(tm, __shfl_xor(tm, 32));

      if (__any(tm > m_run + 8.0f)) {  // defer-max (T13)
        float mn = fmaxf(m_run, tm);
        float alpha = fast_exp2(m_run - mn);
        m_run = mn;
        l_run *= alpha;
#pragma unroll
        for (int i = 0; i < 16; ++i) { accO[0][i] *= alpha; accO[1][i] *= alpha; }
      }
    }
    {
      f32x16 es;
#pragma unroll
      for (int i = 0; i < 16; ++i) {
        float e0 = fast_exp2(s0[i] - m_run);
        float e1 = fast_exp2(s1[i] - m_run);
        s0[i] = e0; s1[i] = e1;
        es[i] = e0 + e1;
      }
#pragma unroll
      for (int i = 0; i < 8; ++i) es[i] += es[i + 8];
#pragma unroll
      for (int i = 0; i < 4; ++i) es[i] += es[i + 4];
      float ps = (es[0] + es[1]) + (es[2] + es[3]);
      ps += __shfl_xor(ps, 32);
      l_run += ps;
    }

    // ---- pack P ----
    uint4v pk[4];
#pragma unroll
    for (int ks = 0; ks < 4; ++ks) {
      int o = 8 * (ks & 1);
      const f32x16& sv = (ks < 2) ? s0 : s1;
      pk[ks][0] = cvt_pk_bf16(sv[o + 0], sv[o + 1]);
      pk[ks][1] = cvt_pk_bf16(sv[o + 2], sv[o + 3]);
      pk[ks][2] = cvt_pk_bf16(sv[o + 4], sv[o + 5]);
      pk[ks][3] = cvt_pk_bf16(sv[o + 6], sv[o + 7]);
    }

    // ---- O += Vt-frag . P ----
    __builtin_amdgcn_s_setprio(1);
#pragma unroll
    for (int ks = 0; ks < 4; ++ks) {
      short8 pf = __builtin_bit_cast(short8, pk[ks]);
      short8 vf0 = *(const short8*)(vq + foff[ks]);
      short8 vf1 = *(const short8*)(vq + foff[ks] + 4096);
      accO[0] = __builtin_amdgcn_mfma_f32_32x32x16_bf16(vf0, pf, accO[0], 0, 0, 0);
      accO[1] = __builtin_amdgcn_mfma_f32_32x32x16_bf16(vf1, pf, accO[1], 0, 0, 0);
    }
    __builtin_amdgcn_s_setprio(0);
    __syncthreads();  // single barrier: prefetch drained; buffers swap
  }

  float inv = 1.0f / l_run;
  float* orow = out + ((size_t)b_ * 2048 + i0 + w * 32 + q) * 1024 + h * 64;
#pragma unroll
  for (int vh = 0; vh < 2; ++vh) {
#pragma unroll
    for (int c = 0; c < 4; ++c) {
      f32x4 o;
      o[0] = accO[vh][4 * c + 0] * inv;
      o[1] = accO[vh][4 * c + 1] * inv;
      o[2] = accO[vh][4 * c + 2] * inv;
      o[3] = accO[vh][4 * c + 3] * inv;
      *(f32x4*)(orow + vh * 32 + 8 * c + 4 * hi) = o;
    }
  }
}

extern "C" void kernel_launch(void* const* d_in, const int* in_sizes, int n_in,
                              void* d_out, int out_size, void* d_ws, size_t ws_size,
                              hipStream_t stream) {
  (void)in_sizes; (void)n_in; (void)out_size; (void)ws_size;
  const float* hs        = (const float*)d_in[0];
  const float* mask      = (const float*)d_in[1];
  const int*   seg_ids   = (const int*)d_in[2];
  const float* Wq        = (const float*)d_in[3];
  const float* bq        = (const float*)d_in[4];
  const float* Wk        = (const float*)d_in[5];
  const float* Wv        = (const float*)d_in[6];
  const float* bv        = (const float*)d_in[7];
  const float* seg_table = (const float*)d_in[8];
  const float* bqs       = (const float*)d_in[9];
  float* out = (float*)d_out;
  char* ws = (char*)d_ws;

  unsigned short* hsb  = (unsigned short*)(ws + 0);         // 16 MiB
  unsigned short* Wcat = (unsigned short*)(ws + 16777216);  // 6 MiB
  unsigned short* Qaug = (unsigned short*)(ws + 23068672);  // 32 MiB
  unsigned short* Kaug = (unsigned short*)(ws + 56623104);  // 32 MiB
  unsigned short* Vt   = (unsigned short*)(ws + 90177536);  // 16 MiB

  k_prep<<<dim3(9728), dim3(256), 0, stream>>>(hs, Wq, Wk, Wv, seg_ids, seg_table,
                                               hsb, Wcat, Kaug);
  k_gemm<<<dim3(24, 64), dim3(256), 0, stream>>>(hsb, Wcat, bq, bv, bqs, Qaug, Kaug, Vt);
  k_attn<<<dim3(8, 16, 4), dim3(512), 0, stream>>>(Qaug, Kaug, Vt, mask, out);
}

// Round 17
// 251.227 us; speedup vs baseline: 1.0501x; 1.0111x over previous
//
#include <hip/hip_runtime.h>
#include <cstdint>
#include <cmath>

#define RLN2 1.44269504088896340736f

typedef __attribute__((ext_vector_type(8))) short short8;
typedef __attribute__((ext_vector_type(4))) short short4v;
typedef __attribute__((ext_vector_type(4))) float f32x4;
typedef __attribute__((ext_vector_type(16))) float f32x16;
typedef __attribute__((ext_vector_type(4))) unsigned int uint4v;
typedef __attribute__((ext_vector_type(2))) unsigned int uint2v;

__device__ __forceinline__ unsigned short f2bf(float f) {
  unsigned int u = __float_as_uint(f);
  u += 0x7fffu + ((u >> 16) & 1u);
  return (unsigned short)(u >> 16);
}

__device__ __forceinline__ unsigned int cvt_pk_bf16(float lo, float hi) {
  unsigned int r;
  asm("v_cvt_pk_bf16_f32 %0, %1, %2" : "=v"(r) : "v"(lo), "v"(hi));
  return r;
}

__device__ __forceinline__ float fast_exp2(float x) {
#if __has_builtin(__builtin_amdgcn_exp2f)
  return __builtin_amdgcn_exp2f(x);
#else
  return exp2f(x);
#endif
}

__device__ __forceinline__ void gload16(const void* g, void* l) {
  __builtin_amdgcn_global_load_lds(
      (const __attribute__((address_space(1))) unsigned int*)g,
      (__attribute__((address_space(3))) unsigned int*)l,
      16, 0, 0);
}

// ---------------- fused prep: hs->bf16, W->bf16, seg fill (one launch) ----------------
// blocks [0,4096): hs convert; [4096,5632): W convert; [5632,9728): seg fill.
// seg fill writes Kaug[tok*128 + 64+d] only -> disjoint from gemm's Kaug writes,
// so prep runs BEFORE gemm.
__global__ void __launch_bounds__(256) k_prep(const float* __restrict__ hs,
                                              const float* __restrict__ Wq,
                                              const float* __restrict__ Wk,
                                              const float* __restrict__ Wv,
                                              const int* __restrict__ seg_ids,
                                              const float* __restrict__ seg_table,
                                              unsigned short* __restrict__ hsb,
                                              unsigned short* __restrict__ Wcat,
                                              unsigned short* __restrict__ Kaug) {
  int blk = blockIdx.x;
  if (blk < 4096) {
    size_t i = (size_t)blk * 256 + threadIdx.x;
    const float4* s = (const float4*)hs + i * 2;
    float4 a = s[0], b = s[1];
    short8 o;
    o[0] = (short)f2bf(a.x); o[1] = (short)f2bf(a.y); o[2] = (short)f2bf(a.z); o[3] = (short)f2bf(a.w);
    o[4] = (short)f2bf(b.x); o[5] = (short)f2bf(b.y); o[6] = (short)f2bf(b.z); o[7] = (short)f2bf(b.w);
    ((short8*)hsb)[i] = o;
  } else if (blk < 5632) {
    size_t i = (size_t)(blk - 4096) * 256 + threadIdx.x;
    int e = (int)(i * 8);
    int n = e >> 10, c = e & 1023;
    const float* row = (n < 1024) ? (Wq + (size_t)n * 1024)
                     : (n < 2048) ? (Wk + (size_t)(n - 1024) * 1024)
                                  : (Wv + (size_t)(n - 2048) * 1024);
    const float4* s = (const float4*)(row + c);
    float4 a = s[0], b = s[1];
    short8 o;
    o[0] = (short)f2bf(a.x); o[1] = (short)f2bf(a.y); o[2] = (short)f2bf(a.z); o[3] = (short)f2bf(a.w);
    o[4] = (short)f2bf(b.x); o[5] = (short)f2bf(b.y); o[6] = (short)f2bf(b.z); o[7] = (short)f2bf(b.w);
    ((short8*)Wcat)[i] = o;
  } else {
    size_t i = (size_t)(blk - 5632) * 256 + threadIdx.x;
    int e = (int)(i * 8);
    int jl = e >> 10;
    int r  = e & 1023;
    int sid = seg_ids[jl];
    const float4* s = (const float4*)(seg_table + (size_t)sid * 1024 + r);
    float4 a = s[0], b = s[1];
    short8 o;
    o[0] = (short)f2bf(a.x); o[1] = (short)f2bf(a.y); o[2] = (short)f2bf(a.z); o[3] = (short)f2bf(a.w);
    o[4] = (short)f2bf(b.x); o[5] = (short)f2bf(b.y); o[6] = (short)f2bf(b.z); o[7] = (short)f2bf(b.w);
    int b_ = jl >> 11, j = jl & 2047;
    int h = r >> 6, d = r & 63;
    size_t off = ((size_t)(b_ * 16 + h) * 2048 + j) * 128 + 64 + d;
    *(short8*)(Kaug + off) = o;
  }
}

// ---------------- fused QKV GEMM (NT) ----------------
// R13 structure (single-buffered 2-barrier K-loop, 16KB LDS, 8 blocks/CU) +
// T1 XCD-chunked bijective blockIdx swizzle (1536 % 8 == 0): each XCD gets 192
// consecutive logical blocks = 8 complete m-rows -> A-panel reuse is XCD-local.
// Q/K blocks (seg<2): SWAPPED operands mfma(W,hs) -> 8B packed stores.
// V blocks (seg==2): original order, k-permuted 8B Vt stores.
__global__ void __launch_bounds__(256) k_gemm(const unsigned short* __restrict__ A,
                                              const unsigned short* __restrict__ Bw,
                                              const float* __restrict__ bq,
                                              const float* __restrict__ bv,
                                              const float* __restrict__ bqs,
                                              unsigned short* __restrict__ Qaug,
                                              unsigned short* __restrict__ Kaug,
                                              unsigned short* __restrict__ Vt) {
  __shared__ unsigned short As[128 * 32];
  __shared__ unsigned short Bs[128 * 32];
  int bid = blockIdx.x;
  int swz = (bid & 7) * 192 + (bid >> 3);  // bijection on [0,1536)
  int n0 = (swz % 24) * 128;
  int m0 = (swz / 24) * 128;
  int tid = threadIdx.x;
  int w = tid >> 6, lane = tid & 63;
  int wr = (w >> 1) * 64, wc = (w & 1) * 64;
  int rA = lane & 15;
  int kg = (lane >> 4) * 16;
  int seg = n0 >> 10;  // 0=q, 1=k, 2=v
  f32x4 acc[4][4] = {};
  const char* Ab = (const char*)A;
  const char* Bb = (const char*)Bw;

  for (int kt = 0; kt < 32; ++kt) {
    int kb0 = kt * 64;
#pragma unroll
    for (int c = 0; c < 2; ++c) {
      int chunk = w * 2 + c;
      int y = chunk * 1024 + lane * 16;
      int row = y >> 6, colb = y & 63;
      gload16(Ab + (size_t)(m0 + row) * 2048 + kb0 + colb, (char*)As + chunk * 1024);
      gload16(Bb + (size_t)(n0 + row) * 2048 + kb0 + colb, (char*)Bs + chunk * 1024);
    }
    __syncthreads();
    short8 af[4], bfr[4];
#pragma unroll
    for (int m = 0; m < 4; ++m)
      af[m] = *(const short8*)((const char*)As + (wr + m * 16 + rA) * 64 + kg);
#pragma unroll
    for (int n = 0; n < 4; ++n)
      bfr[n] = *(const short8*)((const char*)Bs + (wc + n * 16 + rA) * 64 + kg);
    if (seg == 2) {
#pragma unroll
      for (int m = 0; m < 4; ++m)
#pragma unroll
        for (int n = 0; n < 4; ++n)
          acc[m][n] = __builtin_amdgcn_mfma_f32_16x16x32_bf16(af[m], bfr[n], acc[m][n], 0, 0, 0);
    } else {
#pragma unroll
      for (int m = 0; m < 4; ++m)
#pragma unroll
        for (int n = 0; n < 4; ++n)
          acc[m][n] = __builtin_amdgcn_mfma_f32_16x16x32_bf16(bfr[n], af[m], acc[m][n], 0, 0, 0);
    }
    __syncthreads();
  }

  int colbase = n0 & 1023;
  int g = lane >> 4;
  if (seg == 2) {
    // original layout: lane owns feature o=colbase+wc+n*16+(lane&15), tokens m*16+g*4+r
#pragma unroll
    for (int n = 0; n < 4; ++n) {
      int o = colbase + wc + n * 16 + (lane & 15);
      int h = o >> 6, d = o & 63;
      float bias = bv[o];
#pragma unroll
      for (int m = 0; m < 4; ++m) {
        int i = m0 + wr + m * 16 + g * 4;  // r=0 token
        int b_ = i >> 11, sdx = i & 2047;
        int bh = b_ * 16 + h;
        int pos = (sdx & ~63) + 32 * ((m >> 1) & 1) + 16 * (m & 1) + 8 * (g & 1) + 4 * ((g >> 1) & 1);
        short4v pv;
#pragma unroll
        for (int r = 0; r < 4; ++r)
          pv[r] = (short)f2bf(acc[m][n][r] + bias);
        *(short4v*)(Vt + (size_t)bh * 131072 + (size_t)d * 2048 + pos) = pv;
      }
    }
  } else {
    // swapped layout: lane owns token i=m0+wr+m*16+(lane&15), features n*16+g*4+r
    int tok16 = lane & 15, g4 = g * 4;
#pragma unroll
    for (int m = 0; m < 4; ++m) {
      int i = m0 + wr + m * 16 + tok16;
      int b_ = i >> 11, sdx = i & 2047;
#pragma unroll
      for (int n = 0; n < 4; ++n) {
        int o0 = colbase + wc + n * 16 + g4;
        int h = o0 >> 6, d0 = o0 & 63;
        size_t tok = (size_t)(b_ * 16 + h) * 2048 + sdx;
        if (seg == 0) {
          f32x4 bqv = *(const f32x4*)(bq + o0);
          f32x4 bqs4 = *(const f32x4*)(bqs + o0);
          float qv0 = acc[m][n][0] + bqv[0], qv1 = acc[m][n][1] + bqv[1];
          float qv2 = acc[m][n][2] + bqv[2], qv3 = acc[m][n][3] + bqv[3];
          const float sc = 0.125f * RLN2;
          uint2v p1;
          p1[0] = cvt_pk_bf16(qv0 * sc, qv1 * sc);
          p1[1] = cvt_pk_bf16(qv2 * sc, qv3 * sc);
          *(uint2v*)(Qaug + tok * 128 + d0) = p1;
          uint2v p2;
          p2[0] = cvt_pk_bf16((qv0 + bqs4[0]) * RLN2, (qv1 + bqs4[1]) * RLN2);
          p2[1] = cvt_pk_bf16((qv2 + bqs4[2]) * RLN2, (qv3 + bqs4[3]) * RLN2);
          *(uint2v*)(Qaug + tok * 128 + 64 + d0) = p2;
        } else {
          uint2v p1;
          p1[0] = cvt_pk_bf16(acc[m][n][0], acc[m][n][1]);
          p1[1] = cvt_pk_bf16(acc[m][n][2], acc[m][n][3]);
          *(uint2v*)(Kaug + tok * 128 + d0) = p1;
        }
      }
    }
  }
}

// ---------------- flash attention, 32x32x16 MFMA, 32 q-rows/wave ----------------
// R9/R13 VERBATIM (proven 159.5us): 512 thr / 8 waves / 256 q-rows per block,
// K 2x16K + V 2x8K double buffer, prefetch at tile start, ONE end-of-tile barrier.
__global__ void __launch_bounds__(512, 4) k_attn(const unsigned short* __restrict__ Qaug,
                                                 const unsigned short* __restrict__ Kaug,
                                                 const unsigned short* __restrict__ Vt,
                                                 const float* __restrict__ mask,
                                                 float* __restrict__ out) {
  __shared__ char smem[49152];
  char* Ksb = smem;          // 2 x 16K
  char* Vsb = smem + 32768;  // 2 x 8K

  int qt = blockIdx.x, h = blockIdx.y, b_ = blockIdx.z;
  int bh = b_ * 16 + h;
  int i0 = qt * 256;
  int tid = threadIdx.x, w = tid >> 6, lane = tid & 63;
  int q = lane & 31, hi = lane >> 5;
  int swzq = (q & 7) << 4;
  const char* Qg = (const char*)Qaug + (size_t)bh * 2048 * 256;
  const char* Kg = (const char*)Kaug + (size_t)bh * 2048 * 256;
  const char* Vg = (const char*)Vt + (size_t)bh * 64 * 4096;
  const float* maskb = mask + (size_t)b_ * 2048;

  int foff[8];
#pragma unroll
  for (int ds = 0; ds < 8; ++ds)
    foff[ds] = (ds * 32 + hi * 16) ^ swzq;

  int kst_row = lane >> 4, kst_x = (lane & 15) * 16;
  int vst_dv = lane >> 3;
  int vst_x = ((lane & 7) * 16) ^ ((vst_dv & 7) << 4);

  // ---- stage tile 0 ----
#pragma unroll
  for (int c = 0; c < 2; ++c) {
    int ck = w * 2 + c;
    int krow = ck * 4 + kst_row;
    gload16(Kg + (size_t)krow * 256 + (kst_x ^ ((krow & 7) << 4)), Ksb + ck * 1024);
  }
  {
    int dv = w * 8 + vst_dv;
    gload16(Vg + (size_t)dv * 4096 + vst_x, Vsb + w * 1024);
  }

  short8 qf[8];
  {
    const char* qrow = Qg + (size_t)(i0 + w * 32 + q) * 256 + hi * 16;
#pragma unroll
    for (int ds = 0; ds < 8; ++ds)
      qf[ds] = *(const short8*)(qrow + ds * 32);
  }
  __syncthreads();  // K0/V0 resident

  float m_run = -1e30f, l_run = 0.f;
  f32x16 accO[2] = {};

  for (int t = 0; t < 32; ++t) {
    int cur = t & 1, nxt = cur ^ 1;
    int j0 = t * 64;
    if (t < 31) {
      int jn = j0 + 64;
      char* kd = Ksb + nxt * 16384;
      char* vd = Vsb + nxt * 8192;
#pragma unroll
      for (int c = 0; c < 2; ++c) {
        int ck = w * 2 + c;
        int krow = ck * 4 + kst_row;
        gload16(Kg + (size_t)(jn + krow) * 256 + (kst_x ^ ((krow & 7) << 4)), kd + ck * 1024);
      }
      {
        int dv = w * 8 + vst_dv;
        gload16(Vg + (size_t)dv * 4096 + jn * 2 + vst_x, vd + w * 1024);
      }
    }
    const char* kq = Ksb + cur * 16384 + q * 256;
    const char* vq = Vsb + cur * 8192 + q * 128;

    // ---- S^T = K . Q^T ----
    f32x16 s0 = {}, s1 = {};
    __builtin_amdgcn_s_setprio(1);
#pragma unroll
    for (int ds = 0; ds < 8; ++ds) {
      short8 kf0 = *(const short8*)(kq + foff[ds]);
      short8 kf1 = *(const short8*)(kq + foff[ds] + 8192);
      s0 = __builtin_amdgcn_mfma_f32_32x32x16_bf16(kf0, qf[ds], s0, 0, 0, 0);
      s1 = __builtin_amdgcn_mfma_f32_32x32x16_bf16(kf1, qf[ds], s1, 0, 0, 0);
    }
    __builtin_amdgcn_s_setprio(0);

    // ---- mask add via fma(mv, RLN2, s) ----
#pragma unroll
    for (int c = 0; c < 4; ++c) {
      f32x4 mv0 = *(const f32x4*)(maskb + j0 + 8 * c + 4 * hi);
      f32x4 mv1 = *(const f32x4*)(maskb + j0 + 32 + 8 * c + 4 * hi);
#pragma unroll
      for (int r = 0; r < 4; ++r) {
        s0[4 * c + r] = fmaf(mv0[r], RLN2, s0[4 * c + r]);
        s1[4 * c + r] = fmaf(mv1[r], RLN2, s1[4 * c + r]);
      }
    }

    // ---- online softmax ----
    {
      f32x16 mx;
#pragma unroll
      for (int i = 0; i < 16; ++i) mx[i] = fmaxf(s0[i], s1[i]);
#pragma unroll
      for (int i = 0; i < 8; ++i) mx[i] = fmaxf(mx[i], mx[i + 8]);
#pragma unroll
      for (int i = 0; i < 4; ++i) mx[i] = fmaxf(mx[i], mx[i + 4]);
      float tm = fmaxf(fmaxf(mx[0], mx[1]), fmaxf(mx[2], mx[3]));
      tm = fmaxf(tm, __shfl_xor(tm, 32));

      if (__any(tm > m_run + 8.0f)) {  // defer-max (T13)
        float mn = fmaxf(m_run, tm);
        float alpha = fast_exp2(m_run - mn);
        m_run = mn;
        l_run *= alpha;
#pragma unroll
        for (int i = 0; i < 16; ++i) { accO[0][i] *= alpha; accO[1][i] *= alpha; }
      }
    }
    {
      f32x16 es;
#pragma unroll
      for (int i = 0; i < 16; ++i) {
        float e0 = fast_exp2(s0[i] - m_run);
        float e1 = fast_exp2(s1[i] - m_run);
        s0[i] = e0; s1[i] = e1;
        es[i] = e0 + e1;
      }
#pragma unroll
      for (int i = 0; i < 8; ++i) es[i] += es[i + 8];
#pragma unroll
      for (int i = 0; i < 4; ++i) es[i] += es[i + 4];
      float ps = (es[0] + es[1]) + (es[2] + es[3]);
      ps += __shfl_xor(ps, 32);
      l_run += ps;
    }

    // ---- pack P ----
    uint4v pk[4];
#pragma unroll
    for (int ks = 0; ks < 4; ++ks) {
      int o = 8 * (ks & 1);
      const f32x16& sv = (ks < 2) ? s0 : s1;
      pk[ks][0] = cvt_pk_bf16(sv[o + 0], sv[o + 1]);
      pk[ks][1] = cvt_pk_bf16(sv[o + 2], sv[o + 3]);
      pk[ks][2] = cvt_pk_bf16(sv[o + 4], sv[o + 5]);
      pk[ks][3] = cvt_pk_bf16(sv[o + 6], sv[o + 7]);
    }

    // ---- O += Vt-frag . P ----
    __builtin_amdgcn_s_setprio(1);
#pragma unroll
    for (int ks = 0; ks < 4; ++ks) {
      short8 pf = __builtin_bit_cast(short8, pk[ks]);
      short8 vf0 = *(const short8*)(vq + foff[ks]);
      short8 vf1 = *(const short8*)(vq + foff[ks] + 4096);
      accO[0] = __builtin_amdgcn_mfma_f32_32x32x16_bf16(vf0, pf, accO[0], 0, 0, 0);
      accO[1] = __builtin_amdgcn_mfma_f32_32x32x16_bf16(vf1, pf, accO[1], 0, 0, 0);
    }
    __builtin_amdgcn_s_setprio(0);
    __syncthreads();  // single barrier: prefetch drained; buffers swap
  }

  float inv = 1.0f / l_run;
  float* orow = out + ((size_t)b_ * 2048 + i0 + w * 32 + q) * 1024 + h * 64;
#pragma unroll
  for (int vh = 0; vh < 2; ++vh) {
#pragma unroll
    for (int c = 0; c < 4; ++c) {
      f32x4 o;
      o[0] = accO[vh][4 * c + 0] * inv;
      o[1] = accO[vh][4 * c + 1] * inv;
      o[2] = accO[vh][4 * c + 2] * inv;
      o[3] = accO[vh][4 * c + 3] * inv;
      *(f32x4*)(orow + vh * 32 + 8 * c + 4 * hi) = o;
    }
  }
}

extern "C" void kernel_launch(void* const* d_in, const int* in_sizes, int n_in,
                              void* d_out, int out_size, void* d_ws, size_t ws_size,
                              hipStream_t stream) {
  (void)in_sizes; (void)n_in; (void)out_size; (void)ws_size;
  const float* hs        = (const float*)d_in[0];
  const float* mask      = (const float*)d_in[1];
  const int*   seg_ids   = (const int*)d_in[2];
  const float* Wq        = (const float*)d_in[3];
  const float* bq        = (const float*)d_in[4];
  const float* Wk        = (const float*)d_in[5];
  const float* Wv        = (const float*)d_in[6];
  const float* bv        = (const float*)d_in[7];
  const float* seg_table = (const float*)d_in[8];
  const float* bqs       = (const float*)d_in[9];
  float* out = (float*)d_out;
  char* ws = (char*)d_ws;

  unsigned short* hsb  = (unsigned short*)(ws + 0);         // 16 MiB
  unsigned short* Wcat = (unsigned short*)(ws + 16777216);  // 6 MiB
  unsigned short* Qaug = (unsigned short*)(ws + 23068672);  // 32 MiB
  unsigned short* Kaug = (unsigned short*)(ws + 56623104);  // 32 MiB
  unsigned short* Vt   = (unsigned short*)(ws + 90177536);  // 16 MiB

  k_prep<<<dim3(9728), dim3(256), 0, stream>>>(hs, Wq, Wk, Wv, seg_ids, seg_table,
                                               hsb, Wcat, Kaug);
  k_gemm<<<dim3(1536), dim3(256), 0, stream>>>(hsb, Wcat, bq, bv, bqs, Qaug, Kaug, Vt);
  k_attn<<<dim3(8, 16, 4), dim3(512), 0, stream>>>(Qaug, Kaug, Vt, mask, out);
}

// Round 18
// 241.833 us; speedup vs baseline: 1.0909x; 1.0388x over previous
//
#include <hip/hip_runtime.h>
#include <cstdint>
#include <cmath>

#define RLN2 1.44269504088896340736f

typedef __attribute__((ext_vector_type(8))) short short8;
typedef __attribute__((ext_vector_type(4))) short short4v;
typedef __attribute__((ext_vector_type(4))) float f32x4;
typedef __attribute__((ext_vector_type(16))) float f32x16;
typedef __attribute__((ext_vector_type(4))) unsigned int uint4v;
typedef __attribute__((ext_vector_type(2))) unsigned int uint2v;

__device__ __forceinline__ unsigned short f2bf(float f) {
  unsigned int u = __float_as_uint(f);
  u += 0x7fffu + ((u >> 16) & 1u);
  return (unsigned short)(u >> 16);
}

__device__ __forceinline__ unsigned int cvt_pk_bf16(float lo, float hi) {
  unsigned int r;
  asm("v_cvt_pk_bf16_f32 %0, %1, %2" : "=v"(r) : "v"(lo), "v"(hi));
  return r;
}

__device__ __forceinline__ float fast_exp2(float x) {
#if __has_builtin(__builtin_amdgcn_exp2f)
  return __builtin_amdgcn_exp2f(x);
#else
  return exp2f(x);
#endif
}

__device__ __forceinline__ void gload16(const void* g, void* l) {
  __builtin_amdgcn_global_load_lds(
      (const __attribute__((address_space(1))) unsigned int*)g,
      (__attribute__((address_space(3))) unsigned int*)l,
      16, 0, 0);
}

// ---------------- fused prep: hs->bf16, W->bf16, seg fill (one launch) ----------------
// blocks [0,4096): hs convert; [4096,5632): W convert; [5632,9728): seg fill.
// seg fill writes Kaug[tok*128 + 64+d] only -> disjoint from gemm's Kaug writes,
// so prep runs BEFORE gemm.
__global__ void __launch_bounds__(256) k_prep(const float* __restrict__ hs,
                                              const float* __restrict__ Wq,
                                              const float* __restrict__ Wk,
                                              const float* __restrict__ Wv,
                                              const int* __restrict__ seg_ids,
                                              const float* __restrict__ seg_table,
                                              unsigned short* __restrict__ hsb,
                                              unsigned short* __restrict__ Wcat,
                                              unsigned short* __restrict__ Kaug) {
  int blk = blockIdx.x;
  if (blk < 4096) {
    size_t i = (size_t)blk * 256 + threadIdx.x;
    const float4* s = (const float4*)hs + i * 2;
    float4 a = s[0], b = s[1];
    short8 o;
    o[0] = (short)f2bf(a.x); o[1] = (short)f2bf(a.y); o[2] = (short)f2bf(a.z); o[3] = (short)f2bf(a.w);
    o[4] = (short)f2bf(b.x); o[5] = (short)f2bf(b.y); o[6] = (short)f2bf(b.z); o[7] = (short)f2bf(b.w);
    ((short8*)hsb)[i] = o;
  } else if (blk < 5632) {
    size_t i = (size_t)(blk - 4096) * 256 + threadIdx.x;
    int e = (int)(i * 8);
    int n = e >> 10, c = e & 1023;
    const float* row = (n < 1024) ? (Wq + (size_t)n * 1024)
                     : (n < 2048) ? (Wk + (size_t)(n - 1024) * 1024)
                                  : (Wv + (size_t)(n - 2048) * 1024);
    const float4* s = (const float4*)(row + c);
    float4 a = s[0], b = s[1];
    short8 o;
    o[0] = (short)f2bf(a.x); o[1] = (short)f2bf(a.y); o[2] = (short)f2bf(a.z); o[3] = (short)f2bf(a.w);
    o[4] = (short)f2bf(b.x); o[5] = (short)f2bf(b.y); o[6] = (short)f2bf(b.z); o[7] = (short)f2bf(b.w);
    ((short8*)Wcat)[i] = o;
  } else {
    size_t i = (size_t)(blk - 5632) * 256 + threadIdx.x;
    int e = (int)(i * 8);
    int jl = e >> 10;
    int r  = e & 1023;
    int sid = seg_ids[jl];
    const float4* s = (const float4*)(seg_table + (size_t)sid * 1024 + r);
    float4 a = s[0], b = s[1];
    short8 o;
    o[0] = (short)f2bf(a.x); o[1] = (short)f2bf(a.y); o[2] = (short)f2bf(a.z); o[3] = (short)f2bf(a.w);
    o[4] = (short)f2bf(b.x); o[5] = (short)f2bf(b.y); o[6] = (short)f2bf(b.z); o[7] = (short)f2bf(b.w);
    int b_ = jl >> 11, j = jl & 2047;
    int h = r >> 6, d = r & 63;
    size_t off = ((size_t)(b_ * 16 + h) * 2048 + j) * 128 + 64 + d;
    *(short8*)(Kaug + off) = o;
  }
}

// ---------------- fused QKV GEMM (NT) ----------------
// R16 verbatim: single-buffered 2-barrier K-loop, 16KB LDS, 8 blocks/CU,
// T1 XCD-chunked bijective blockIdx swizzle (1536 % 8 == 0).
// Q/K blocks (seg<2): SWAPPED operands mfma(W,hs) -> 8B packed stores.
// V blocks (seg==2): original order, k-permuted 8B Vt stores.
__global__ void __launch_bounds__(256) k_gemm(const unsigned short* __restrict__ A,
                                              const unsigned short* __restrict__ Bw,
                                              const float* __restrict__ bq,
                                              const float* __restrict__ bv,
                                              const float* __restrict__ bqs,
                                              unsigned short* __restrict__ Qaug,
                                              unsigned short* __restrict__ Kaug,
                                              unsigned short* __restrict__ Vt) {
  __shared__ unsigned short As[128 * 32];
  __shared__ unsigned short Bs[128 * 32];
  int bid = blockIdx.x;
  int swz = (bid & 7) * 192 + (bid >> 3);  // bijection on [0,1536)
  int n0 = (swz % 24) * 128;
  int m0 = (swz / 24) * 128;
  int tid = threadIdx.x;
  int w = tid >> 6, lane = tid & 63;
  int wr = (w >> 1) * 64, wc = (w & 1) * 64;
  int rA = lane & 15;
  int kg = (lane >> 4) * 16;
  int seg = n0 >> 10;  // 0=q, 1=k, 2=v
  f32x4 acc[4][4] = {};
  const char* Ab = (const char*)A;
  const char* Bb = (const char*)Bw;

  for (int kt = 0; kt < 32; ++kt) {
    int kb0 = kt * 64;
#pragma unroll
    for (int c = 0; c < 2; ++c) {
      int chunk = w * 2 + c;
      int y = chunk * 1024 + lane * 16;
      int row = y >> 6, colb = y & 63;
      gload16(Ab + (size_t)(m0 + row) * 2048 + kb0 + colb, (char*)As + chunk * 1024);
      gload16(Bb + (size_t)(n0 + row) * 2048 + kb0 + colb, (char*)Bs + chunk * 1024);
    }
    __syncthreads();
    short8 af[4], bfr[4];
#pragma unroll
    for (int m = 0; m < 4; ++m)
      af[m] = *(const short8*)((const char*)As + (wr + m * 16 + rA) * 64 + kg);
#pragma unroll
    for (int n = 0; n < 4; ++n)
      bfr[n] = *(const short8*)((const char*)Bs + (wc + n * 16 + rA) * 64 + kg);
    if (seg == 2) {
#pragma unroll
      for (int m = 0; m < 4; ++m)
#pragma unroll
        for (int n = 0; n < 4; ++n)
          acc[m][n] = __builtin_amdgcn_mfma_f32_16x16x32_bf16(af[m], bfr[n], acc[m][n], 0, 0, 0);
    } else {
#pragma unroll
      for (int m = 0; m < 4; ++m)
#pragma unroll
        for (int n = 0; n < 4; ++n)
          acc[m][n] = __builtin_amdgcn_mfma_f32_16x16x32_bf16(bfr[n], af[m], acc[m][n], 0, 0, 0);
    }
    __syncthreads();
  }

  int colbase = n0 & 1023;
  int g = lane >> 4;
  if (seg == 2) {
    // original layout: lane owns feature o=colbase+wc+n*16+(lane&15), tokens m*16+g*4+r
#pragma unroll
    for (int n = 0; n < 4; ++n) {
      int o = colbase + wc + n * 16 + (lane & 15);
      int h = o >> 6, d = o & 63;
      float bias = bv[o];
#pragma unroll
      for (int m = 0; m < 4; ++m) {
        int i = m0 + wr + m * 16 + g * 4;  // r=0 token
        int b_ = i >> 11, sdx = i & 2047;
        int bh = b_ * 16 + h;
        int pos = (sdx & ~63) + 32 * ((m >> 1) & 1) + 16 * (m & 1) + 8 * (g & 1) + 4 * ((g >> 1) & 1);
        short4v pv;
#pragma unroll
        for (int r = 0; r < 4; ++r)
          pv[r] = (short)f2bf(acc[m][n][r] + bias);
        *(short4v*)(Vt + (size_t)bh * 131072 + (size_t)d * 2048 + pos) = pv;
      }
    }
  } else {
    // swapped layout: lane owns token i=m0+wr+m*16+(lane&15), features n*16+g*4+r
    int tok16 = lane & 15, g4 = g * 4;
#pragma unroll
    for (int m = 0; m < 4; ++m) {
      int i = m0 + wr + m * 16 + tok16;
      int b_ = i >> 11, sdx = i & 2047;
#pragma unroll
      for (int n = 0; n < 4; ++n) {
        int o0 = colbase + wc + n * 16 + g4;
        int h = o0 >> 6, d0 = o0 & 63;
        size_t tok = (size_t)(b_ * 16 + h) * 2048 + sdx;
        if (seg == 0) {
          f32x4 bqv = *(const f32x4*)(bq + o0);
          f32x4 bqs4 = *(const f32x4*)(bqs + o0);
          float qv0 = acc[m][n][0] + bqv[0], qv1 = acc[m][n][1] + bqv[1];
          float qv2 = acc[m][n][2] + bqv[2], qv3 = acc[m][n][3] + bqv[3];
          const float sc = 0.125f * RLN2;
          uint2v p1;
          p1[0] = cvt_pk_bf16(qv0 * sc, qv1 * sc);
          p1[1] = cvt_pk_bf16(qv2 * sc, qv3 * sc);
          *(uint2v*)(Qaug + tok * 128 + d0) = p1;
          uint2v p2;
          p2[0] = cvt_pk_bf16((qv0 + bqs4[0]) * RLN2, (qv1 + bqs4[1]) * RLN2);
          p2[1] = cvt_pk_bf16((qv2 + bqs4[2]) * RLN2, (qv3 + bqs4[3]) * RLN2);
          *(uint2v*)(Qaug + tok * 128 + 64 + d0) = p2;
        } else {
          uint2v p1;
          p1[0] = cvt_pk_bf16(acc[m][n][0], acc[m][n][1]);
          p1[1] = cvt_pk_bf16(acc[m][n][2], acc[m][n][3]);
          *(uint2v*)(Kaug + tok * 128 + d0) = p1;
        }
      }
    }
  }
}

// ---------------- flash attention, 32x32x16 MFMA, 32 q-rows/wave ----------------
// R9/R13 inner loop VERBATIM (proven 159.5us). NEW: 1D grid of 512 with T1
// XCD-chunked swizzle (512 % 8 == 0): the 8 qt-blocks sharing one bh's K/V
// stream land on the SAME XCD -> one L2 copy serves all 8 readers. Grid is
// exactly fully co-resident (2 blocks/CU), so temporal co-residency (R5's
// failure mode) cannot be disturbed -- placement-only change.
__global__ void __launch_bounds__(512, 4) k_attn(const unsigned short* __restrict__ Qaug,
                                                 const unsigned short* __restrict__ Kaug,
                                                 const unsigned short* __restrict__ Vt,
                                                 const float* __restrict__ mask,
                                                 float* __restrict__ out) {
  __shared__ char smem[49152];
  char* Ksb = smem;          // 2 x 16K
  char* Vsb = smem + 32768;  // 2 x 8K

  int bid = blockIdx.x;
  int swz = (bid & 7) * 64 + (bid >> 3);  // bijection on [0,512)
  int bh = swz >> 3, qt = swz & 7;        // 8 consecutive swz share one bh
  int h = bh & 15, b_ = bh >> 4;
  int i0 = qt * 256;
  int tid = threadIdx.x, w = tid >> 6, lane = tid & 63;
  int q = lane & 31, hi = lane >> 5;
  int swzq = (q & 7) << 4;
  const char* Qg = (const char*)Qaug + (size_t)bh * 2048 * 256;
  const char* Kg = (const char*)Kaug + (size_t)bh * 2048 * 256;
  const char* Vg = (const char*)Vt + (size_t)bh * 64 * 4096;
  const float* maskb = mask + (size_t)b_ * 2048;

  int foff[8];
#pragma unroll
  for (int ds = 0; ds < 8; ++ds)
    foff[ds] = (ds * 32 + hi * 16) ^ swzq;

  int kst_row = lane >> 4, kst_x = (lane & 15) * 16;
  int vst_dv = lane >> 3;
  int vst_x = ((lane & 7) * 16) ^ ((vst_dv & 7) << 4);

  // ---- stage tile 0 ----
#pragma unroll
  for (int c = 0; c < 2; ++c) {
    int ck = w * 2 + c;
    int krow = ck * 4 + kst_row;
    gload16(Kg + (size_t)krow * 256 + (kst_x ^ ((krow & 7) << 4)), Ksb + ck * 1024);
  }
  {
    int dv = w * 8 + vst_dv;
    gload16(Vg + (size_t)dv * 4096 + vst_x, Vsb + w * 1024);
  }

  short8 qf[8];
  {
    const char* qrow = Qg + (size_t)(i0 + w * 32 + q) * 256 + hi * 16;
#pragma unroll
    for (int ds = 0; ds < 8; ++ds)
      qf[ds] = *(const short8*)(qrow + ds * 32);
  }
  __syncthreads();  // K0/V0 resident

  float m_run = -1e30f, l_run = 0.f;
  f32x16 accO[2] = {};

  for (int t = 0; t < 32; ++t) {
    int cur = t & 1, nxt = cur ^ 1;
    int j0 = t * 64;
    if (t < 31) {
      int jn = j0 + 64;
      char* kd = Ksb + nxt * 16384;
      char* vd = Vsb + nxt * 8192;
#pragma unroll
      for (int c = 0; c < 2; ++c) {
        int ck = w * 2 + c;
        int krow = ck * 4 + kst_row;
        gload16(Kg + (size_t)(jn + krow) * 256 + (kst_x ^ ((krow & 7) << 4)), kd + ck * 1024);
      }
      {
        int dv = w * 8 + vst_dv;
        gload16(Vg + (size_t)dv * 4096 + jn * 2 + vst_x, vd + w * 1024);
      }
    }
    const char* kq = Ksb + cur * 16384 + q * 256;
    const char* vq = Vsb + cur * 8192 + q * 128;

    // ---- S^T = K . Q^T ----
    f32x16 s0 = {}, s1 = {};
    __builtin_amdgcn_s_setprio(1);
#pragma unroll
    for (int ds = 0; ds < 8; ++ds) {
      short8 kf0 = *(const short8*)(kq + foff[ds]);
      short8 kf1 = *(const short8*)(kq + foff[ds] + 8192);
      s0 = __builtin_amdgcn_mfma_f32_32x32x16_bf16(kf0, qf[ds], s0, 0, 0, 0);
      s1 = __builtin_amdgcn_mfma_f32_32x32x16_bf16(kf1, qf[ds], s1, 0, 0, 0);
    }
    __builtin_amdgcn_s_setprio(0);

    // ---- mask add via fma(mv, RLN2, s) ----
#pragma unroll
    for (int c = 0; c < 4; ++c) {
      f32x4 mv0 = *(const f32x4*)(maskb + j0 + 8 * c + 4 * hi);
      f32x4 mv1 = *(const f32x4*)(maskb + j0 + 32 + 8 * c + 4 * hi);
#pragma unroll
      for (int r = 0; r < 4; ++r) {
        s0[4 * c + r] = fmaf(mv0[r], RLN2, s0[4 * c + r]);
        s1[4 * c + r] = fmaf(mv1[r], RLN2, s1[4 * c + r]);
      }
    }

    // ---- online softmax ----
    {
      f32x16 mx;
#pragma unroll
      for (int i = 0; i < 16; ++i) mx[i] = fmaxf(s0[i], s1[i]);
#pragma unroll
      for (int i = 0; i < 8; ++i) mx[i] = fmaxf(mx[i], mx[i + 8]);
#pragma unroll
      for (int i = 0; i < 4; ++i) mx[i] = fmaxf(mx[i], mx[i + 4]);
      float tm = fmaxf(fmaxf(mx[0], mx[1]), fmaxf(mx[2], mx[3]));
      tm = fmaxf(tm, __shfl_xor(tm, 32));

      if (__any(tm > m_run + 8.0f)) {  // defer-max (T13)
        float mn = fmaxf(m_run, tm);
        float alpha = fast_exp2(m_run - mn);
        m_run = mn;
        l_run *= alpha;
#pragma unroll
        for (int i = 0; i < 16; ++i) { accO[0][i] *= alpha; accO[1][i] *= alpha; }
      }
    }
    {
      f32x16 es;
#pragma unroll
      for (int i = 0; i < 16; ++i) {
        float e0 = fast_exp2(s0[i] - m_run);
        float e1 = fast_exp2(s1[i] - m_run);
        s0[i] = e0; s1[i] = e1;
        es[i] = e0 + e1;
      }
#pragma unroll
      for (int i = 0; i < 8; ++i) es[i] += es[i + 8];
#pragma unroll
      for (int i = 0; i < 4; ++i) es[i] += es[i + 4];
      float ps = (es[0] + es[1]) + (es[2] + es[3]);
      ps += __shfl_xor(ps, 32);
      l_run += ps;
    }

    // ---- pack P ----
    uint4v pk[4];
#pragma unroll
    for (int ks = 0; ks < 4; ++ks) {
      int o = 8 * (ks & 1);
      const f32x16& sv = (ks < 2) ? s0 : s1;
      pk[ks][0] = cvt_pk_bf16(sv[o + 0], sv[o + 1]);
      pk[ks][1] = cvt_pk_bf16(sv[o + 2], sv[o + 3]);
      pk[ks][2] = cvt_pk_bf16(sv[o + 4], sv[o + 5]);
      pk[ks][3] = cvt_pk_bf16(sv[o + 6], sv[o + 7]);
    }

    // ---- O += Vt-frag . P ----
    __builtin_amdgcn_s_setprio(1);
#pragma unroll
    for (int ks = 0; ks < 4; ++ks) {
      short8 pf = __builtin_bit_cast(short8, pk[ks]);
      short8 vf0 = *(const short8*)(vq + foff[ks]);
      short8 vf1 = *(const short8*)(vq + foff[ks] + 4096);
      accO[0] = __builtin_amdgcn_mfma_f32_32x32x16_bf16(vf0, pf, accO[0], 0, 0, 0);
      accO[1] = __builtin_amdgcn_mfma_f32_32x32x16_bf16(vf1, pf, accO[1], 0, 0, 0);
    }
    __builtin_amdgcn_s_setprio(0);
    __syncthreads();  // single barrier: prefetch drained; buffers swap
  }

  float inv = 1.0f / l_run;
  float* orow = out + ((size_t)b_ * 2048 + i0 + w * 32 + q) * 1024 + h * 64;
#pragma unroll
  for (int vh = 0; vh < 2; ++vh) {
#pragma unroll
    for (int c = 0; c < 4; ++c) {
      f32x4 o;
      o[0] = accO[vh][4 * c + 0] * inv;
      o[1] = accO[vh][4 * c + 1] * inv;
      o[2] = accO[vh][4 * c + 2] * inv;
      o[3] = accO[vh][4 * c + 3] * inv;
      *(f32x4*)(orow + vh * 32 + 8 * c + 4 * hi) = o;
    }
  }
}

extern "C" void kernel_launch(void* const* d_in, const int* in_sizes, int n_in,
                              void* d_out, int out_size, void* d_ws, size_t ws_size,
                              hipStream_t stream) {
  (void)in_sizes; (void)n_in; (void)out_size; (void)ws_size;
  const float* hs        = (const float*)d_in[0];
  const float* mask      = (const float*)d_in[1];
  const int*   seg_ids   = (const int*)d_in[2];
  const float* Wq        = (const float*)d_in[3];
  const float* bq        = (const float*)d_in[4];
  const float* Wk        = (const float*)d_in[5];
  const float* Wv        = (const float*)d_in[6];
  const float* bv        = (const float*)d_in[7];
  const float* seg_table = (const float*)d_in[8];
  const float* bqs       = (const float*)d_in[9];
  float* out = (float*)d_out;
  char* ws = (char*)d_ws;

  unsigned short* hsb  = (unsigned short*)(ws + 0);         // 16 MiB
  unsigned short* Wcat = (unsigned short*)(ws + 16777216);  // 6 MiB
  unsigned short* Qaug = (unsigned short*)(ws + 23068672);  // 32 MiB
  unsigned short* Kaug = (unsigned short*)(ws + 56623104);  // 32 MiB
  unsigned short* Vt   = (unsigned short*)(ws + 90177536);  // 16 MiB

  k_prep<<<dim3(9728), dim3(256), 0, stream>>>(hs, Wq, Wk, Wv, seg_ids, seg_table,
                                               hsb, Wcat, Kaug);
  k_gemm<<<dim3(1536), dim3(256), 0, stream>>>(hsb, Wcat, bq, bv, bqs, Qaug, Kaug, Vt);
  k_attn<<<dim3(512), dim3(512), 0, stream>>>(Qaug, Kaug, Vt, mask, out);
}